// Round 3
// baseline (866.701 us; speedup 1.0000x reference)
//
#include <hip/hip_runtime.h>

// GPUHungarianMatcher R12 — exact replication of the reference's degenerate
// "_lsa" (minv reset every inner iteration => chain-Dijkstra). One block
// (4 waves) per batch. R12 = R11 (validated spine + parallel vdelta scatter
// epilogue) + three spine trims:
//  (1) ui0 = 0.0 at row start (PROOF: u[i] == 0 when row i's search begins —
//      rows are processed once and u[i] only grows during row i's own search;
//      recU records the pre-value, so the epilogue math is unchanged).
//      rowDat shrinks to float2 rowTgt {tx,ty} (never written after init);
//      the row-start read is PREFETCHED during the previous row's epilogue
//      (right after barrier E), hiding its ~120cy latency under epilogue
//      work. The rowDat.u write is deleted (nothing read it anymore).
//  (2) the WINNING LANE writes the mailbox directly {minhi, its klo, its
//      bidx} — drops 2 serial readlanes from the fast path (bidx embeds tid
//      => unique winner; the tie slow path computes the winning lane).
//  (3) used-column poison moved to f32: cf = used ? +INF : cf (1 cndmask)
//      instead of cur = DINF (2 f64 cndmasks). +INF propagates through the
//      f64 subs; used candidates tie among themselves at +INF with the same
//      first-k index resolution; a wave can never be all-used (used < 256 <
//      512 cols/wave) so the global winner is always a finite free column —
//      selection-identical to the DINF scheme.
//
// Exactness invariants (unchanged from the R2-R11 absmax-0 lineage):
//  * cost fp32: fabsf(qx-tX)+fabsf(qy-tY)+np_, reduced fp64: ((double)cf-u)-v
//  * scans read only PRE-search u/v (path rows/cols distinct, p injective)
//  * argmin: fmin + smallest-k among exact equals (ctz of ==-mask; +/-0 both
//    compare equal) = np.argmin first occurrence
//  * pairwise tournament: left wins ties at every level => same winner as
//    the left-to-right scan (min + earliest index, keys lexicographic)
//  * u update: single add of prefix-difference on pre-search u (recU)
//  * v update: vdelta scatter, values bitwise-identical to the serial loop
//  * softmax bitwise-identical to the R2 tree (same thread mapping)
//  * free-flag: colDat[j].tx = -1.0f iff column j unmatched (real tx >= 0)

constexpr int B = 8;
constexpr int Q = 2048;        // columns (queries)
constexpr int T = 256;         // rows (targets)
constexpr int NT = 256;        // threads per block (4 waves)
constexpr int KPT = Q / NT;    // 8 columns per thread, j = 1 + tid + k*256
constexpr int NW = NT / 64;

struct __align__(16) CD { double u; float tx, ty; };   // one ds_read_b128

__device__ __forceinline__ unsigned wave_min_u32_dpp(unsigned a) {
  // full-wave u32 min: row_shr 1,2,4,8 then row_bcast15, row_bcast31;
  // invalid source lanes keep old (bound_ctrl=false, masks 0xf) = identity.
  int v = (int)a, t;
  t = __builtin_amdgcn_update_dpp(v, v, 0x111, 0xf, 0xf, false);
  v = ((unsigned)t < (unsigned)v) ? t : v;
  t = __builtin_amdgcn_update_dpp(v, v, 0x112, 0xf, 0xf, false);
  v = ((unsigned)t < (unsigned)v) ? t : v;
  t = __builtin_amdgcn_update_dpp(v, v, 0x114, 0xf, 0xf, false);
  v = ((unsigned)t < (unsigned)v) ? t : v;
  t = __builtin_amdgcn_update_dpp(v, v, 0x118, 0xf, 0xf, false);
  v = ((unsigned)t < (unsigned)v) ? t : v;
  t = __builtin_amdgcn_update_dpp(v, v, 0x142, 0xf, 0xf, false);
  v = ((unsigned)t < (unsigned)v) ? t : v;
  t = __builtin_amdgcn_update_dpp(v, v, 0x143, 0xf, 0xf, false);
  v = ((unsigned)t < (unsigned)v) ? t : v;
  return (unsigned)__builtin_amdgcn_readlane(v, 63);   // lane 63 = global min
}

__launch_bounds__(NT, 1)
__global__ void hungarian_r12(const float* __restrict__ outs,
                              const float* __restrict__ tgts,
                              int* __restrict__ out) {
  const int b = blockIdx.x;
  const int tid = threadIdx.x;
  const int lane = tid & 63;
  const int wv = tid >> 6;

  __shared__ CD colDat[Q + 1];      // colDat[j] = {u[p[j]], tx[p[j]-1], ty[p[j]-1]}
                                    // tx = -1.0f marks a FREE column
  __shared__ float2 rowTgt[T + 1];  // rowTgt[r] = {tx[r-1], ty[r-1]} (read-only
                                    // after init; row-start u is always 0.0)
  __shared__ short p[Q + 1];        // p[j]: row matched to col j (1-based), 0 free
  __shared__ uint4 pk[2][NW];       // packed mailbox {khi, klo, idx, 0} (parity)
  __shared__ double vdelta[Q];      // per-column v-delta scatter; 0.0 = no update
  __shared__ int ansArr[T];
  __shared__ double s_rv[NW];
  __shared__ float sh_f;

  const size_t qbase = (size_t)b * Q;
  const size_t tbase = (size_t)b * T;

  // ---- stage per-thread column data (fixed mapping j = 1 + tid + k*256) ----
  float xs[KPT], qx[KPT], qy[KPT];
#pragma unroll
  for (int k = 0; k < KPT; ++k) {
    const size_t o = (qbase + tid + k * NT) * 3;
    xs[k] = outs[o];
    qx[k] = outs[o + 1];
    qy[k] = outs[o + 2];
  }
  {
    const size_t o = (tbase + tid) * 3;   // T == NT: one target per thread
    rowTgt[tid + 1] = make_float2(tgts[o + 1], tgts[o + 2]);
    if (tid == 0) rowTgt[0] = make_float2(0.f, 0.f);
  }

  // ---- softmax over Q logits (bitwise-identical to the R2-passing tree) ----
  float lmax = xs[0];
#pragma unroll
  for (int k = 1; k < KPT; ++k) lmax = fmaxf(lmax, xs[k]);
  for (int off = 32; off > 0; off >>= 1) lmax = fmaxf(lmax, __shfl_down(lmax, off));
  if ((tid & 63) == 0) s_rv[tid >> 6] = (double)lmax;
  __syncthreads();
  if (tid == 0) {
    float m2 = (float)s_rv[0];
    for (int w = 1; w < NW; ++w) m2 = fmaxf(m2, (float)s_rv[w]);
    sh_f = m2;
  }
  __syncthreads();
  const float smax = sh_f;
  float ex[KPT];
  float lsum = 0.f;
#pragma unroll
  for (int k = 0; k < KPT; ++k) { ex[k] = expf(xs[k] - smax); lsum += ex[k]; }
  for (int off = 32; off > 0; off >>= 1) lsum += __shfl_down(lsum, off);
  if ((tid & 63) == 0) s_rv[tid >> 6] = (double)lsum;
  __syncthreads();
  if (tid == 0) {
    float s2 = 0.f;
    for (int w = 0; w < NW; ++w) s2 += (float)s_rv[w];
    sh_f = s2;
  }
  __syncthreads();
  const float ssum = sh_f;
  float np_[KPT];
#pragma unroll
  for (int k = 0; k < KPT; ++k) np_[k] = -(ex[k] / ssum);

  // ---- init state ----
  for (int j = tid; j <= Q; j += NT) {
    p[j] = 0;
    CD c0; c0.u = 0.0; c0.tx = -1.0f; c0.ty = 0.0f;   // all columns free
    colDat[j] = c0;
  }
  double vreg[KPT];   // v[j] for this thread's 8 columns (static indices only)
#pragma unroll
  for (int k = 0; k < KPT; ++k) {
    vreg[k] = 0.0;
    vdelta[tid + (k << 8)] = 0.0;
  }
  __syncthreads();

  const float FINF = __int_as_float(0x7f800000);   // +inf poison for used cols
  float2 nxtT = rowTgt[1];                         // prefetch row 1's target

  // ---- main loop over rows ----
  for (int i = 1; i <= T; ++i) {
    unsigned usedMask = 0;
    double D = 0.0;
    int i0 = i;
    double ui0 = 0.0;                // PROOF: u[i] == 0 at row i's search start
    float tX = nxtT.x, tY = nxtT.y;  // prefetched during previous epilogue
    int s = 0, S;
    int j1v = 0;                         // column selected at the previous step
    int recRow = 0, recCol = 0, recPrev = 0;   // thread t records step t's state
    double recU = 0.0, recD = 0.0;
    float recTX = 0.f, recTY = 0.f;

    for (;;) {
      // record this step's pre-state on thread s (off the dependency spine);
      // recPrev = column selected at step s-1 (== R9's visCol[s])
      if (tid == s) {
        recRow = i0; recU = ui0; recTX = tX; recTY = tY; recD = D; recPrev = j1v;
      }

      // scan my 8 columns: cur = ((double)cf - u[i0]) - v[j]; used columns
      // poisoned at the f32 stage (cf = +inf => cur = +inf, never wins)
      double cv[KPT];
#pragma unroll
      for (int k = 0; k < KPT; ++k) {
        float cf = fabsf(qx[k] - tX) + fabsf(qy[k] - tY) + np_[k];
        if (usedMask & (1u << k)) cf = FINF;
        cv[k] = ((double)cf - ui0) - vreg[k];
      }
      // within-lane argmin: fmin tree for the value, then parallel ==-mask +
      // ctz => smallest k among exact equals (first occurrence; +/-0 match)
      const double m01 = fmin(cv[0], cv[1]), m23 = fmin(cv[2], cv[3]);
      const double m45 = fmin(cv[4], cv[5]), m67 = fmin(cv[6], cv[7]);
      const double m03 = fmin(m01, m23), m47 = fmin(m45, m67);
      double bval = fmin(m03, m47);
      unsigned emsk = 0;
#pragma unroll
      for (int k = 0; k < KPT; ++k) emsk |= (cv[k] == bval) ? (1u << k) : 0u;
      const int bk = (int)__builtin_ctz(emsk);   // emsk != 0 always
      int bidx = 1 + tid + (bk << 8);

      // monotonic u64 bit-key of the per-lane winner (canonicalize -0 -> +0)
      bval += 0.0;
      const long long bb = __double_as_longlong(bval);
      const unsigned long long key = (unsigned long long)bb ^
          ((bb < 0) ? 0xFFFFFFFFFFFFFFFFull : 0x8000000000000000ull);
      const unsigned khi = (unsigned)(key >> 32);
      const unsigned klo = (unsigned)key;

      // wave argmin: DPP min on hi32, ballot for winner, exact ties slow path
      const unsigned minhi = wave_min_u32_dpp(khi);
      const unsigned long long mask = __ballot(khi == minhi);
      int wl;
      if (__popcll(mask) == 1) {
        wl = (int)__ffsll(mask) - 1;
      } else {
        unsigned wklo = 0xffffffffu; int widx = 0x7fffffff; wl = 0;
        unsigned long long mm = mask;
        while (mm) {
          const int l = (int)__ffsll(mm) - 1; mm &= mm - 1;
          const unsigned lo2 = (unsigned)__builtin_amdgcn_readlane((int)klo, l);
          const int ix2 = __builtin_amdgcn_readlane(bidx, l);
          if (lo2 < wklo || (lo2 == wklo && ix2 < widx)) {
            wklo = lo2; widx = ix2; wl = l;
          }
        }
      }
      // the WINNING LANE writes its own {minhi, klo, bidx}: no readlanes
      // (bidx embeds tid => unique winner; slow path's wl holds the
      // lexicographic (klo, bidx) minimum among khi ties)
      const int par = s & 1;
      if (lane == wl) pk[par][wv] = make_uint4(minhi, klo, (unsigned)bidx, 0u);
      __syncthreads();            // the only per-step barrier

      // read the 4 packed candidates, then IMMEDIATELY prefetch their colDat
      const uint4 c0v = pk[par][0];
      const uint4 c1v = pk[par][1];
      const uint4 c2v = pk[par][2];
      const uint4 c3v = pk[par][3];
      const CD cd0 = colDat[(int)c0v.z];   // prefetch: latency overlaps combine
      const CD cd1 = colDat[(int)c1v.z];
      const CD cd2 = colDat[(int)c2v.z];
      const CD cd3 = colDat[(int)c3v.z];

      // cross-wave pairwise tournament (left wins ties at every level ==
      // same winner as the left-to-right scan of R5-R11)
      const unsigned long long k0b = ((unsigned long long)c0v.x << 32) | c0v.y;
      const unsigned long long k1b = ((unsigned long long)c1v.x << 32) | c1v.y;
      const unsigned long long k2b = ((unsigned long long)c2v.x << 32) | c2v.y;
      const unsigned long long k3b = ((unsigned long long)c3v.x << 32) | c3v.y;
      const int j0b = (int)c0v.z, j1bb = (int)c1v.z;
      const int j2b = (int)c2v.z, j3b = (int)c3v.z;
      // level 1 (pairs 01 and 23, independent)
      const bool w01 = (k1b < k0b) || (k1b == k0b && j1bb < j0b);
      const unsigned long long k01 = w01 ? k1b : k0b;
      const int j01 = w01 ? j1bb : j0b;
      const bool w23 = (k3b < k2b) || (k3b == k2b && j3b < j2b);
      const unsigned long long k23 = w23 ? k3b : k2b;
      const int j23 = w23 ? j3b : j2b;
      // level 2 (final)
      const bool wf = (k23 < k01) || (k23 == k01 && j23 < j01);
      const unsigned long long bkk = wf ? k23 : k01;
      const int j1 = wf ? j23 : j01;          // selected column, 1-based
      // CD selection folded along the same tournament (depth 2)
      CD cdA; cdA.u = w01 ? cd1.u : cd0.u;
      cdA.tx = w01 ? cd1.tx : cd0.tx; cdA.ty = w01 ? cd1.ty : cd0.ty;
      CD cdB; cdB.u = w23 ? cd3.u : cd2.u;
      cdB.tx = w23 ? cd3.tx : cd2.tx; cdB.ty = w23 ? cd3.ty : cd2.ty;
      CD cd; cd.u = wf ? cdB.u : cdA.u;
      cd.tx = wf ? cdB.tx : cdA.tx; cd.ty = wf ? cdB.ty : cdA.ty;

      // invert bit-key -> delta (bitwise identical on every thread)
      const long long db = (long long)((bkk & 0x8000000000000000ull)
                                           ? (bkk ^ 0x8000000000000000ull) : ~bkk);
      D += __longlong_as_double(db);
      if (tid == ((j1 - 1) & 255)) usedMask |= 1u << ((j1 - 1) >> 8);
      if (tid == s) recCol = j1;
      const int pj1 = (int)p[j1];   // off-path: feeds only next step's recorder
      j1v = j1;
      ++s;
      if (cd.tx < 0.0f) { S = s; break; }   // free column => path complete
      ui0 = cd.u; tX = cd.tx; tY = cd.ty; i0 = pj1;
    }

    // ---- epilogue: O(path) deferred updates from recorded registers ----
    __syncthreads();              // E: all waves done stepping
    nxtT = rowTgt[i < T ? i + 1 : T];   // prefetch next row's target (read-only
                                        // array => latency hides under epilogue)
    const double Dfin = D;
    if (tid < S) {
      p[recCol] = (short)recRow;                  // augment (rows/cols distinct)
      const double unew = recU + (Dfin - recD);   // same single-add as R3-R11
      CD c2; c2.u = unew; c2.tx = recTX; c2.ty = recTY;
      colDat[recCol] = c2;                        // refresh cache (tx >= 0)
      if (tid >= 1) {
        // column of step tid-1 (== R9's visCol[tid]) receives Dfin - recD
        // (== Dfin - visD[tid]); path columns distinct => no collision
        vdelta[recPrev - 1] = Dfin - recD;
      }
    }
    __syncthreads();              // F: epilogue writes visible
    // owners apply their 8 slots: static indices, stride-8B conflict-free
    // reads; 0.0 slots are bitwise no-ops (x -= 0.0 == x, incl. -0.0).
#pragma unroll
    for (int k = 0; k < KPT; ++k) {
      const double dv = vdelta[tid + (k << 8)];
      vreg[k] -= dv;
      vdelta[tid + (k << 8)] = 0.0;   // reset; ordered vs next scatter by E
    }
    // next row's search reads (colDat/p) ordered by F; vdelta slots are
    // re-written only after the next E barrier
  }
  __syncthreads();

  // ---- extract assignment, rank-sort (distinct values), write int32 ----
  for (int j = 1 + tid; j <= Q; j += NT) {
    const int pi = (int)p[j];
    if (pi > 0) ansArr[pi - 1] = j - 1;
  }
  __syncthreads();
  const int a = ansArr[tid];
  int rank = 0;
  for (int t2 = 0; t2 < T; ++t2) rank += (ansArr[t2] < a) ? 1 : 0;
  out[(size_t)b * T + rank] = a;                      // row_ind (sorted query idx)
  out[(size_t)B * T + (size_t)b * T + rank] = tid;    // col_ind (target idx)
}

extern "C" void kernel_launch(void* const* d_in, const int* in_sizes, int n_in,
                              void* d_out, int out_size, void* d_ws, size_t ws_size,
                              hipStream_t stream) {
  const float* outs = (const float*)d_in[0];   // (8, 2048, 3) fp32
  const float* tgts = (const float*)d_in[1];   // (8, 256, 3) fp32
  int* out = (int*)d_out;                      // row_ind (8,256) ++ col_ind (8,256)
  hungarian_r12<<<B, NT, 0, stream>>>(outs, tgts, out);
}